// Round 2
// baseline (456.816 us; speedup 1.0000x reference)
//
#include <hip/hip_runtime.h>
#include <hip/hip_bf16.h>
#include <stdint.h>

// ---------------------------------------------------------------------------
// 2-layer GAT (inference) on MI355X, dtype-adaptive.
// Round-16 changes vs round-15 (349.4 us; aggregate4 regressed 62.6->68.6):
//  * Aggregation redesigned as XCD-sliced: feature dim split into 32-col
//    slices (64B/row). slice = blockIdx.x % NS rides round-robin block->XCD
//    dispatch so each XCD's gather working set is 3.2MB and FITS ITS 4MB L2
//    (was 25.6MB -> every XCD refetched all of h1; FETCH 195MB ~= 8x25.6MB).
//    One dst per wave (divergence-free), 8 edge-slots x 8 col-lanes x 8B,
//    slot-combine via shfl_xor(8/16/32). Single templated kernel serves
//    layer 1 (D=256, NS=8, ELU) and layer 2 (D=64, NS=2, dyn out dtype).
//  * wbuf restructured to head-major planes [H][E] (weight4 writes 4
//    coalesced streams) so per-slice w reads are contiguous.
//  * Round-15's 2-edges-in-flight aggregate bodies dropped (BW-ceiling, not
//    latency: doubled MLP lowered the rate).
// ---------------------------------------------------------------------------

typedef __attribute__((ext_vector_type(8))) short bf16x8;
typedef __attribute__((ext_vector_type(4))) float f32x4;

__device__ __forceinline__ float bf2f(__hip_bfloat16 v) { return __bfloat162float(v); }
__device__ __forceinline__ float bfbits2f(unsigned short s) {
  union { uint32_t u; float f; } v; v.u = ((uint32_t)s) << 16; return v.f;
}
__device__ __forceinline__ unsigned short f2bfbits(float f) {
  union { float f; uint32_t u; } v; v.f = f;
  uint32_t u = v.u;
  return (unsigned short)((u + 0x7fffu + ((u >> 16) & 1u)) >> 16);  // RNE
}

template <bool BF>
__device__ __forceinline__ float loadF(const void* p, size_t i) {
  if (BF) return bf2f(((const __hip_bfloat16*)p)[i]);
  return ((const float*)p)[i];
}
template <bool I64>
__device__ __forceinline__ int loadI(const void* p, size_t i) {
  if (I64) return (int)((const long long*)p)[i];
  return ((const int*)p)[i];
}
__device__ __forceinline__ float lrelu(float v) { return fmaxf(v, 0.2f * v); }

// ----------------- dtype detection (wave-parallel) -------------------------
__global__ void detect_kernel(const uint32_t* __restrict__ xbits,
                              const uint32_t* __restrict__ eibits,
                              int* __restrict__ flags) {
  const int l = threadIdx.x;  // 64 threads
  uint32_t u = xbits[l];
  uint32_t e = (u >> 23) & 0xffu;
  bool plausible = (e < 160u && e > 90u) || (u & 0x7fffffffu) == 0u;
  unsigned long long m1 = __ballot(plausible);
  bool z = (eibits[2 * l + 1] == 0u);
  unsigned long long m2 = __ballot(z);
  if (l == 0) {
    flags[0] = (__popcll(m1) < 32) ? 1 : 0;  // 1 = floats are bf16
    flags[1] = (m2 == ~0ULL) ? 1 : 0;        // 1 = edge_index is int64
  }
}

// ----------------- prep (single dispatch): cast x; transpose W1, W2 --------
__global__ __launch_bounds__(256) void prep_all(
    const void* __restrict__ x, unsigned short* __restrict__ xb, size_t nx,
    const void* __restrict__ W1, unsigned short* __restrict__ w1t, int K1, int N1,
    const void* __restrict__ W2, unsigned short* __restrict__ w2t, int K2, int N2,
    int nb_cast, int nb_t1, const int* __restrict__ flags) {
  const int b = blockIdx.x;
  const bool f = flags[0] != 0;
  if (b < nb_cast) {
    size_t i = ((size_t)b * 256 + threadIdx.x) * 4;
    if (i >= nx) return;
    ushort4 o;
    if (f) {
      o = *(const ushort4*)((const unsigned short*)x + i);
    } else {
      float4 v = *(const float4*)((const float*)x + i);
      o.x = f2bfbits(v.x); o.y = f2bfbits(v.y);
      o.z = f2bfbits(v.z); o.w = f2bfbits(v.w);
    }
    *(ushort4*)(xb + i) = o;
  } else if (b < nb_cast + nb_t1) {
    int idx = (b - nb_cast) * 256 + threadIdx.x;
    if (idx >= K1 * N1) return;
    int k = idx / N1, n = idx - k * N1;
    float v = f ? loadF<true>(W1, idx) : loadF<false>(W1, idx);
    w1t[(size_t)n * K1 + k] = f2bfbits(v);
  } else {
    int idx = (b - nb_cast - nb_t1) * 256 + threadIdx.x;
    if (idx >= K2 * N2) return;
    int k = idx / N2, n = idx - k * N2;
    float v = f ? loadF<true>(W2, idx) : loadF<false>(W2, idx);
    w2t[(size_t)n * K2 + k] = f2bfbits(v);
  }
}

// ----------------- MFMA GEMM + fused attention-dot epilogue ----------------
template <int KC, int NT, int HB>
__global__ __launch_bounds__(256, 4) void gemm_mfma_att(
    const unsigned short* __restrict__ A,   // [M][KC] bf16 bits
    const unsigned short* __restrict__ BT,  // [Htot*64][KC] bf16 bits
    unsigned short* __restrict__ C,         // [M][Htot*64] bf16 bits
    const void* __restrict__ att_s, const void* __restrict__ att_d,
    float* __restrict__ as_o, float* __restrict__ ad_o,
    float* __restrict__ wself_o,
    int M, int Htot, const int* __restrict__ flags) {
  const int lane = threadIdx.x & 63;
  const int col = lane & 15;
  const int quad = lane >> 4;
  const int m0 = blockIdx.x * 64 + (threadIdx.x >> 6) * 16;
  const int n0 = blockIdx.y * (NT * 16);
  const int NCOL = Htot * 64;

  int gm = m0 + col;                 // A row this lane supplies
  if (gm > M - 1) gm = M - 1;        // clamp: garbage only affects guarded rows
  const unsigned short* arow = A + (size_t)gm * KC + quad * 8;
  const unsigned short* bbase = BT + (size_t)(n0 + col) * KC + quad * 8;

  f32x4 acc[NT] = {};
#pragma unroll
  for (int k0 = 0; k0 < KC; k0 += 32) {
    bf16x8 a = *(const bf16x8*)(arow + k0);
#pragma unroll
    for (int s = 0; s < NT; s++) {
      bf16x8 b = *(const bf16x8*)(bbase + (size_t)s * 16 * KC + k0);
      acc[s] = __builtin_amdgcn_mfma_f32_16x16x32_bf16(a, b, acc[s], 0, 0, 0);
    }
  }
  // store C
#pragma unroll
  for (int s = 0; s < NT; s++)
#pragma unroll
    for (int r = 0; r < 4; r++) {
      int m = m0 + quad * 4 + r;
      if (m < M) C[(size_t)m * NCOL + n0 + s * 16 + col] = f2bfbits(acc[s][r]);
    }
  // fused attention dots: head h covers s in [h*SC, (h+1)*SC)
  const int SC = NT / HB;
  const bool f = flags[0] != 0;
#pragma unroll
  for (int h = 0; h < HB; h++) {
    const int gh = blockIdx.y * HB + h;
    float ps[4] = {0.f, 0.f, 0.f, 0.f};
    float pd[4] = {0.f, 0.f, 0.f, 0.f};
#pragma unroll
    for (int j = 0; j < SC; j++) {
      int s = h * SC + j;
      int ci = gh * 64 + j * 16 + col;
      float av = f ? loadF<true>(att_s, ci) : loadF<false>(att_s, ci);
      float dv = f ? loadF<true>(att_d, ci) : loadF<false>(att_d, ci);
#pragma unroll
      for (int r = 0; r < 4; r++) {
        ps[r] += acc[s][r] * av;
        pd[r] += acc[s][r] * dv;
      }
    }
#pragma unroll
    for (int o = 1; o < 16; o <<= 1) {
#pragma unroll
      for (int r = 0; r < 4; r++) {
        ps[r] += __shfl_xor(ps[r], o);
        pd[r] += __shfl_xor(pd[r], o);
      }
    }
    if (col == 0) {
#pragma unroll
      for (int r = 0; r < 4; r++) {
        int m = m0 + quad * 4 + r;
        if (m < M) {
          as_o[m * Htot + gh] = ps[r];
          ad_o[m * Htot + gh] = pd[r];
          wself_o[m * Htot + gh] = __expf(lrelu(ps[r] + pd[r]));  // no max-sub
        }
      }
    }
  }
}

// ----------------- CSR build ------------------------------------------------
__global__ void hist_kernel(const void* __restrict__ ei, int E,
                            int* __restrict__ deg, const int* __restrict__ flags) {
  int e = blockIdx.x * blockDim.x + threadIdx.x;
  if (e >= E) return;
  int d = flags[1] ? loadI<true>(ei, (size_t)E + e) : loadI<false>(ei, (size_t)E + e);
  atomicAdd(&deg[d], 1);
}

__global__ __launch_bounds__(256) void scan_block_sums(const int* __restrict__ deg,
                                                       int* __restrict__ bsum, int n) {
  __shared__ int buf[256];
  const int t = threadIdx.x;
  const int i = blockIdx.x * 256 + t;
  buf[t] = (i < n) ? deg[i] : 0;
  __syncthreads();
  for (int o = 128; o > 0; o >>= 1) {
    if (t < o) buf[t] += buf[t + o];
    __syncthreads();
  }
  if (t == 0) bsum[blockIdx.x] = buf[0];
}

__global__ __launch_bounds__(256) void scan_bsums(int* __restrict__ bsum, int nb) {
  __shared__ int buf[256];
  const int t = threadIdx.x;
  int orig = (t < nb) ? bsum[t] : 0;
  buf[t] = orig;
  __syncthreads();
  for (int o = 1; o < 256; o <<= 1) {
    int v = (t >= o) ? buf[t - o] : 0;
    __syncthreads();
    buf[t] += v;
    __syncthreads();
  }
  if (t < nb) bsum[t] = buf[t] - orig;  // exclusive
}

__global__ __launch_bounds__(256) void scan_finalize(const int* __restrict__ deg,
                                                     const int* __restrict__ bsum,
                                                     int* __restrict__ row_start, int n) {
  __shared__ int buf[256];
  const int t = threadIdx.x;
  const int i = blockIdx.x * 256 + t;
  int v = (i < n) ? deg[i] : 0;
  buf[t] = v;
  __syncthreads();
  for (int o = 1; o < 256; o <<= 1) {
    int x = (t >= o) ? buf[t - o] : 0;
    __syncthreads();
    buf[t] += x;
    __syncthreads();
  }
  if (i < n) row_start[i + 1] = bsum[blockIdx.x] + buf[t];
  if (i == 0) row_start[0] = 0;
}

__global__ void scatter_edges(const void* __restrict__ ei, int E,
                              const int* __restrict__ row_start,
                              int* __restrict__ cursor, int* __restrict__ col_src,
                              int* __restrict__ col_dst,
                              const int* __restrict__ flags) {
  int e = blockIdx.x * blockDim.x + threadIdx.x;
  if (e >= E) return;
  int s, d;
  if (flags[1]) { s = loadI<true>(ei, e);  d = loadI<true>(ei, (size_t)E + e); }
  else          { s = loadI<false>(ei, e); d = loadI<false>(ei, (size_t)E + e); }
  int pos = atomicAdd(&cursor[d], 1);
  int idx = row_start[d] + pos;
  col_src[idx] = s;
  col_dst[idx] = d;
}

// ----------------- edge-parallel softmax weights (coalesced map) -----------
// Writes head-major planes wplanes[h][e] so sliced aggregation reads are
// contiguous per head.
__global__ __launch_bounds__(256) void weight4(
    const int* __restrict__ col_src, const int* __restrict__ col_dst,
    const float4* __restrict__ as4, const float4* __restrict__ ad4,
    float* __restrict__ wplanes, int E) {
  int e = blockIdx.x * 256 + threadIdx.x;
  if (e >= E) return;
  float4 a = as4[col_src[e]];
  float4 b = ad4[col_dst[e]];
  wplanes[e]                 = __expf(lrelu(a.x + b.x));
  wplanes[(size_t)E + e]     = __expf(lrelu(a.y + b.y));
  wplanes[(size_t)2 * E + e] = __expf(lrelu(a.z + b.z));
  wplanes[(size_t)3 * E + e] = __expf(lrelu(a.w + b.w));
}

__global__ __launch_bounds__(256) void weight1(
    const int* __restrict__ col_src, const int* __restrict__ col_dst,
    const float* __restrict__ as_, const float* __restrict__ ad_,
    float* __restrict__ wbuf, int E) {
  int e = blockIdx.x * 256 + threadIdx.x;
  if (e >= E) return;
  wbuf[e] = __expf(lrelu(as_[col_src[e]] + ad_[col_dst[e]]));
}

// ----------------- XCD-sliced aggregation ----------------------------------
// Feature dim split into NS slices of 32 cols (64B). slice = blockIdx.x % NS:
// under round-robin block->XCD dispatch all blocks of a slice share one XCD,
// whose hot gather set is N*64B = 3.2MB -> fits the 4MB per-XCD L2.
// One dst per wave. Lanes: slot = l>>3 (8 edge slots), cl = l&7 (8B of cols).
// Slot partials combined via shfl_xor(8/16/32).
template <int DCOLS, int NS, bool ELU, bool OUT_DYN>
__global__ __launch_bounds__(256) void aggregate_sliced(
    const unsigned short* __restrict__ h_in,   // [N][DCOLS] bf16 bits
    const float* __restrict__ wselfA,          // [N][H]
    const float* __restrict__ wplanes,         // [H][E]
    const int* __restrict__ row_start, const int* __restrict__ col_src,
    const void* __restrict__ bias,
    void* __restrict__ out, int N, int E, const int* __restrict__ flags) {
  constexpr int H = DCOLS / 64;
  const int slice = blockIdx.x % NS;   // XCD-affine
  const int chunk = blockIdx.x / NS;
  const int dst = chunk * 4 + (threadIdx.x >> 6);
  if (dst >= N) return;
  const int l = threadIdx.x & 63;
  const int slot = l >> 3;
  const int cl = l & 7;
  const int h = (slice * 32) >> 6;           // head of this slice
  const int c0 = slice * 32 + cl * 4;        // this lane's 4 columns
  const int rs = row_start[dst];
  const int dg = row_start[dst + 1] - rs;
  const float ws = wselfA[dst * H + h];
  const float* __restrict__ wp = wplanes + (size_t)h * E;

  float a0 = 0.f, a1 = 0.f, a2 = 0.f, a3 = 0.f, p = 0.f;
  if (slot == 0) {
    ushort4 sv = *(const ushort4*)(h_in + (size_t)dst * DCOLS + c0);
    a0 = ws * bfbits2f(sv.x); a1 = ws * bfbits2f(sv.y);
    a2 = ws * bfbits2f(sv.z); a3 = ws * bfbits2f(sv.w);
  }
#pragma unroll 2
  for (int i = slot; i < dg; i += 8) {
    const int idx = rs + i;
    const int sn = col_src[idx];
    const float w = wp[idx];
    p += w;
    ushort4 sv = *(const ushort4*)(h_in + (size_t)sn * DCOLS + c0);
    a0 += w * bfbits2f(sv.x); a1 += w * bfbits2f(sv.y);
    a2 += w * bfbits2f(sv.z); a3 += w * bfbits2f(sv.w);
  }
#pragma unroll
  for (int o = 8; o < 64; o <<= 1) {
    a0 += __shfl_xor(a0, o); a1 += __shfl_xor(a1, o);
    a2 += __shfl_xor(a2, o); a3 += __shfl_xor(a3, o);
    p  += __shfl_xor(p, o);
  }
  if (slot == 0) {
    const float inv = 1.0f / (p + ws + 1e-16f);
    const bool f = flags[0] != 0;
    float b0, b1, b2, b3;
    if (f) {
      b0 = loadF<true>(bias, c0 + 0); b1 = loadF<true>(bias, c0 + 1);
      b2 = loadF<true>(bias, c0 + 2); b3 = loadF<true>(bias, c0 + 3);
    } else {
      b0 = loadF<false>(bias, c0 + 0); b1 = loadF<false>(bias, c0 + 1);
      b2 = loadF<false>(bias, c0 + 2); b3 = loadF<false>(bias, c0 + 3);
    }
    float o0 = a0 * inv + b0, o1 = a1 * inv + b1;
    float o2 = a2 * inv + b2, o3 = a3 * inv + b3;
    if (ELU) {
      o0 = o0 > 0.f ? o0 : __expf(o0) - 1.f;
      o1 = o1 > 0.f ? o1 : __expf(o1) - 1.f;
      o2 = o2 > 0.f ? o2 : __expf(o2) - 1.f;
      o3 = o3 > 0.f ? o3 : __expf(o3) - 1.f;
    }
    if (OUT_DYN && !f) {
      float4 v; v.x = o0; v.y = o1; v.z = o2; v.w = o3;
      *(float4*)((float*)out + (size_t)dst * DCOLS + c0) = v;
    } else {
      ushort4 ov;
      ov.x = f2bfbits(o0); ov.y = f2bfbits(o1);
      ov.z = f2bfbits(o2); ov.w = f2bfbits(o3);
      *(ushort4*)((unsigned short*)out + (size_t)dst * DCOLS + c0) = ov;
    }
  }
}

// ---------------------------------------------------------------------------
extern "C" void kernel_launch(void* const* d_in, const int* in_sizes, int n_in,
                              void* d_out, int out_size, void* d_ws, size_t ws_size,
                              hipStream_t stream) {
  const void* x    = d_in[0];
  const void* ei   = d_in[1];
  const void* W1   = d_in[2];
  const void* as1w = d_in[3];
  const void* ad1w = d_in[4];
  const void* b1   = d_in[5];
  const void* W2   = d_in[6];
  const void* as2w = d_in[7];
  const void* ad2w = d_in[8];
  const void* b2   = d_in[9];

  const int N  = out_size / 64;      // 50000
  const int F  = in_sizes[0] / N;    // 128
  const int E  = in_sizes[1] / 2;    // 800000
  const int H1 = in_sizes[3] / 64;   // 4
  const int D1 = H1 * 64;            // 256
  const int D2 = 64;                 // layer-2 output dim (H2 = 1)

  size_t off = 0;
  auto alloc = [&](size_t bytes) -> void* {
    void* p = (char*)d_ws + off;
    off += (bytes + 255) & ~(size_t)255;
    return p;
  };
  int* flags = (int*)alloc(2 * sizeof(int));
  __hip_bfloat16* h1 = (__hip_bfloat16*)alloc((size_t)N * D1 * 2);
  __hip_bfloat16* x2 = (__hip_bfloat16*)alloc((size_t)N * D1 * 2);
  __hip_bfloat16* h2 = h1;  // h1 dead after layer-1 aggregate; reuse
  unsigned short* xb  = (unsigned short*)alloc((size_t)N * F * 2);   // x in bf16
  unsigned short* w1t = (unsigned short*)alloc((size_t)D1 * F * 2);  // [256][128]
  unsigned short* w2t = (unsigned short*)alloc((size_t)D2 * D1 * 2); // [64][256]
  float* as1 = (float*)alloc((size_t)N * H1 * 4);
  float* ad1 = (float*)alloc((size_t)N * H1 * 4);
  float* wself1 = (float*)alloc((size_t)N * H1 * 4);
  float* as2 = (float*)alloc((size_t)N * 4);
  float* ad2 = (float*)alloc((size_t)N * 4);
  float* wself2 = (float*)alloc((size_t)N * 4);
  int* zero_region = (int*)alloc((size_t)2 * N * 4);  // deg | cursor
  int* deg = zero_region;
  int* cursor = zero_region + N;
  int* row_start = (int*)alloc((size_t)(N + 1) * 4);
  int* col_src = (int*)alloc((size_t)E * 4);
  int* col_dst = (int*)alloc((size_t)E * 4);
  float* wbuf = (float*)alloc((size_t)E * 4 * 4);  // L1: [4][E] planes; L2 reuses [E]
  int* bsum = (int*)alloc((size_t)256 * 4);
  (void)ws_size; (void)n_in;

  const int nb = (N + 255) / 256;
  const int eb = (E + 255) / 256;
  const int db = (N + 3) / 4;
  const int gb = (N + 63) / 64;

  // ---- dtype detection + CSR build + GEMM prep (single prep dispatch)
  detect_kernel<<<1, 64, 0, stream>>>((const uint32_t*)x, (const uint32_t*)ei, flags);
  hipMemsetAsync(zero_region, 0, (size_t)2 * N * 4, stream);
  hist_kernel<<<eb, 256, 0, stream>>>(ei, E, deg, flags);
  scan_block_sums<<<nb, 256, 0, stream>>>(deg, bsum, N);
  scan_bsums<<<1, 256, 0, stream>>>(bsum, nb);
  scan_finalize<<<nb, 256, 0, stream>>>(deg, bsum, row_start, N);
  scatter_edges<<<eb, 256, 0, stream>>>(ei, E, row_start, cursor, col_src, col_dst, flags);

  const size_t nx = (size_t)N * F;
  const int nb_cast = (int)((nx / 4 + 255) / 256);
  const int nb_t1 = (F * D1 + 255) / 256;
  const int nb_t2 = (D1 * D2 + 255) / 256;
  prep_all<<<nb_cast + nb_t1 + nb_t2, 256, 0, stream>>>(
      x, xb, nx, W1, w1t, F, D1, W2, w2t, D1, D2, nb_cast, nb_t1, flags);

  // ---- layer 1: GEMM 64x128 tiles (grid.y = 2), K=128 unrolled
  gemm_mfma_att<128, 8, 2><<<dim3(gb, 2), 256, 0, stream>>>(
      xb, w1t, (unsigned short*)h1, as1w, ad1w, as1, ad1, wself1, N, H1, flags);
  weight4<<<eb, 256, 0, stream>>>(col_src, col_dst, (const float4*)as1,
                                  (const float4*)ad1, wbuf, E);
  aggregate_sliced<256, 8, true, false><<<db * 8, 256, 0, stream>>>(
      (const unsigned short*)h1, wself1, wbuf, row_start, col_src, b1,
      (void*)x2, N, E, flags);

  // ---- layer 2: GEMM 64x64 tile, K=256 unrolled
  gemm_mfma_att<256, 4, 1><<<dim3(gb, 1), 256, 0, stream>>>(
      (const unsigned short*)x2, w2t, (unsigned short*)h2, as2w, ad2w,
      as2, ad2, wself2, N, 1, flags);
  weight1<<<eb, 256, 0, stream>>>(col_src, col_dst, as2, ad2, wbuf, E);
  aggregate_sliced<64, 2, false, true><<<db * 2, 256, 0, stream>>>(
      (const unsigned short*)h2, wself2, wbuf, row_start, col_src, b2,
      d_out, N, E, flags);
}

// Round 3
// 331.299 us; speedup vs baseline: 1.3789x; 1.3789x over previous
//
#include <hip/hip_runtime.h>
#include <hip/hip_bf16.h>
#include <stdint.h>

// ---------------------------------------------------------------------------
// 2-layer GAT (inference) on MI355X, dtype-adaptive.
// Round-17 changes vs round-16 (456 us regression; round-14 = 349.4 us ref):
//  * Aggregates reverted to the proven round-14 bodies (wave-per-dst, full
//    512B/128B row per edge; XCD slicing abandoned — FETCH did not drop and
//    rate collapsed to 1.6 TB/s).
//  * Softmax weights computed INLINE in the aggregates from the L2-resident
//    as/ad tables (800KB / 200KB): w = exp(lrelu(as[src,h] + ad[dst,h])).
//    weight4 + weight1 dispatches and the wbuf 12.8MB write+read deleted.
//  * col_dst deleted (nothing reads it anymore) — scatter_edges writes only
//    col_src (-3.2MB scattered stores).
//  * hipMemsetAsync folded into detect_zero (block 0 detects dtypes, the
//    rest zero deg|cursor). Dispatch count 14 -> 11.
// ---------------------------------------------------------------------------

typedef __attribute__((ext_vector_type(8))) short bf16x8;
typedef __attribute__((ext_vector_type(4))) float f32x4;

__device__ __forceinline__ float bf2f(__hip_bfloat16 v) { return __bfloat162float(v); }
__device__ __forceinline__ float bfbits2f(unsigned short s) {
  union { uint32_t u; float f; } v; v.u = ((uint32_t)s) << 16; return v.f;
}
__device__ __forceinline__ unsigned short f2bfbits(float f) {
  union { float f; uint32_t u; } v; v.f = f;
  uint32_t u = v.u;
  return (unsigned short)((u + 0x7fffu + ((u >> 16) & 1u)) >> 16);  // RNE
}

template <bool BF>
__device__ __forceinline__ float loadF(const void* p, size_t i) {
  if (BF) return bf2f(((const __hip_bfloat16*)p)[i]);
  return ((const float*)p)[i];
}
template <bool I64>
__device__ __forceinline__ int loadI(const void* p, size_t i) {
  if (I64) return (int)((const long long*)p)[i];
  return ((const int*)p)[i];
}
__device__ __forceinline__ float lrelu(float v) { return fmaxf(v, 0.2f * v); }

// ----------------- dtype detection + workspace zeroing ---------------------
__global__ __launch_bounds__(256) void detect_zero(
    const uint32_t* __restrict__ xbits, const uint32_t* __restrict__ eibits,
    int* __restrict__ flags, int* __restrict__ zero_region, int nzero) {
  if (blockIdx.x == 0) {
    if (threadIdx.x < 64) {
      const int l = threadIdx.x;
      uint32_t u = xbits[l];
      uint32_t e = (u >> 23) & 0xffu;
      bool plausible = (e < 160u && e > 90u) || (u & 0x7fffffffu) == 0u;
      unsigned long long m1 = __ballot(plausible);
      bool z = (eibits[2 * l + 1] == 0u);
      unsigned long long m2 = __ballot(z);
      if (l == 0) {
        flags[0] = (__popcll(m1) < 32) ? 1 : 0;  // 1 = floats are bf16
        flags[1] = (m2 == ~0ULL) ? 1 : 0;        // 1 = edge_index is int64
      }
    }
    return;
  }
  int i = (blockIdx.x - 1) * 256 + threadIdx.x;
  if (i < nzero) zero_region[i] = 0;
}

// ----------------- prep (single dispatch): cast x; transpose W1, W2 --------
__global__ __launch_bounds__(256) void prep_all(
    const void* __restrict__ x, unsigned short* __restrict__ xb, size_t nx,
    const void* __restrict__ W1, unsigned short* __restrict__ w1t, int K1, int N1,
    const void* __restrict__ W2, unsigned short* __restrict__ w2t, int K2, int N2,
    int nb_cast, int nb_t1, const int* __restrict__ flags) {
  const int b = blockIdx.x;
  const bool f = flags[0] != 0;
  if (b < nb_cast) {
    size_t i = ((size_t)b * 256 + threadIdx.x) * 4;
    if (i >= nx) return;
    ushort4 o;
    if (f) {
      o = *(const ushort4*)((const unsigned short*)x + i);
    } else {
      float4 v = *(const float4*)((const float*)x + i);
      o.x = f2bfbits(v.x); o.y = f2bfbits(v.y);
      o.z = f2bfbits(v.z); o.w = f2bfbits(v.w);
    }
    *(ushort4*)(xb + i) = o;
  } else if (b < nb_cast + nb_t1) {
    int idx = (b - nb_cast) * 256 + threadIdx.x;
    if (idx >= K1 * N1) return;
    int k = idx / N1, n = idx - k * N1;
    float v = f ? loadF<true>(W1, idx) : loadF<false>(W1, idx);
    w1t[(size_t)n * K1 + k] = f2bfbits(v);
  } else {
    int idx = (b - nb_cast - nb_t1) * 256 + threadIdx.x;
    if (idx >= K2 * N2) return;
    int k = idx / N2, n = idx - k * N2;
    float v = f ? loadF<true>(W2, idx) : loadF<false>(W2, idx);
    w2t[(size_t)n * K2 + k] = f2bfbits(v);
  }
}

// ----------------- MFMA GEMM + fused attention-dot epilogue ----------------
template <int KC, int NT, int HB>
__global__ __launch_bounds__(256, 4) void gemm_mfma_att(
    const unsigned short* __restrict__ A,   // [M][KC] bf16 bits
    const unsigned short* __restrict__ BT,  // [Htot*64][KC] bf16 bits
    unsigned short* __restrict__ C,         // [M][Htot*64] bf16 bits
    const void* __restrict__ att_s, const void* __restrict__ att_d,
    float* __restrict__ as_o, float* __restrict__ ad_o,
    float* __restrict__ wself_o,
    int M, int Htot, const int* __restrict__ flags) {
  const int lane = threadIdx.x & 63;
  const int col = lane & 15;
  const int quad = lane >> 4;
  const int m0 = blockIdx.x * 64 + (threadIdx.x >> 6) * 16;
  const int n0 = blockIdx.y * (NT * 16);
  const int NCOL = Htot * 64;

  int gm = m0 + col;                 // A row this lane supplies
  if (gm > M - 1) gm = M - 1;        // clamp: garbage only affects guarded rows
  const unsigned short* arow = A + (size_t)gm * KC + quad * 8;
  const unsigned short* bbase = BT + (size_t)(n0 + col) * KC + quad * 8;

  f32x4 acc[NT] = {};
#pragma unroll
  for (int k0 = 0; k0 < KC; k0 += 32) {
    bf16x8 a = *(const bf16x8*)(arow + k0);
#pragma unroll
    for (int s = 0; s < NT; s++) {
      bf16x8 b = *(const bf16x8*)(bbase + (size_t)s * 16 * KC + k0);
      acc[s] = __builtin_amdgcn_mfma_f32_16x16x32_bf16(a, b, acc[s], 0, 0, 0);
    }
  }
  // store C
#pragma unroll
  for (int s = 0; s < NT; s++)
#pragma unroll
    for (int r = 0; r < 4; r++) {
      int m = m0 + quad * 4 + r;
      if (m < M) C[(size_t)m * NCOL + n0 + s * 16 + col] = f2bfbits(acc[s][r]);
    }
  // fused attention dots: head h covers s in [h*SC, (h+1)*SC)
  const int SC = NT / HB;
  const bool f = flags[0] != 0;
#pragma unroll
  for (int h = 0; h < HB; h++) {
    const int gh = blockIdx.y * HB + h;
    float ps[4] = {0.f, 0.f, 0.f, 0.f};
    float pd[4] = {0.f, 0.f, 0.f, 0.f};
#pragma unroll
    for (int j = 0; j < SC; j++) {
      int s = h * SC + j;
      int ci = gh * 64 + j * 16 + col;
      float av = f ? loadF<true>(att_s, ci) : loadF<false>(att_s, ci);
      float dv = f ? loadF<true>(att_d, ci) : loadF<false>(att_d, ci);
#pragma unroll
      for (int r = 0; r < 4; r++) {
        ps[r] += acc[s][r] * av;
        pd[r] += acc[s][r] * dv;
      }
    }
#pragma unroll
    for (int o = 1; o < 16; o <<= 1) {
#pragma unroll
      for (int r = 0; r < 4; r++) {
        ps[r] += __shfl_xor(ps[r], o);
        pd[r] += __shfl_xor(pd[r], o);
      }
    }
    if (col == 0) {
#pragma unroll
      for (int r = 0; r < 4; r++) {
        int m = m0 + quad * 4 + r;
        if (m < M) {
          as_o[m * Htot + gh] = ps[r];
          ad_o[m * Htot + gh] = pd[r];
          wself_o[m * Htot + gh] = __expf(lrelu(ps[r] + pd[r]));  // no max-sub
        }
      }
    }
  }
}

// ----------------- CSR build ------------------------------------------------
__global__ void hist_kernel(const void* __restrict__ ei, int E,
                            int* __restrict__ deg, const int* __restrict__ flags) {
  int e = blockIdx.x * blockDim.x + threadIdx.x;
  if (e >= E) return;
  int d = flags[1] ? loadI<true>(ei, (size_t)E + e) : loadI<false>(ei, (size_t)E + e);
  atomicAdd(&deg[d], 1);
}

__global__ __launch_bounds__(256) void scan_block_sums(const int* __restrict__ deg,
                                                       int* __restrict__ bsum, int n) {
  __shared__ int buf[256];
  const int t = threadIdx.x;
  const int i = blockIdx.x * 256 + t;
  buf[t] = (i < n) ? deg[i] : 0;
  __syncthreads();
  for (int o = 128; o > 0; o >>= 1) {
    if (t < o) buf[t] += buf[t + o];
    __syncthreads();
  }
  if (t == 0) bsum[blockIdx.x] = buf[0];
}

__global__ __launch_bounds__(256) void scan_bsums(int* __restrict__ bsum, int nb) {
  __shared__ int buf[256];
  const int t = threadIdx.x;
  int orig = (t < nb) ? bsum[t] : 0;
  buf[t] = orig;
  __syncthreads();
  for (int o = 1; o < 256; o <<= 1) {
    int v = (t >= o) ? buf[t - o] : 0;
    __syncthreads();
    buf[t] += v;
    __syncthreads();
  }
  if (t < nb) bsum[t] = buf[t] - orig;  // exclusive
}

__global__ __launch_bounds__(256) void scan_finalize(const int* __restrict__ deg,
                                                     const int* __restrict__ bsum,
                                                     int* __restrict__ row_start, int n) {
  __shared__ int buf[256];
  const int t = threadIdx.x;
  const int i = blockIdx.x * 256 + t;
  int v = (i < n) ? deg[i] : 0;
  buf[t] = v;
  __syncthreads();
  for (int o = 1; o < 256; o <<= 1) {
    int x = (t >= o) ? buf[t - o] : 0;
    __syncthreads();
    buf[t] += x;
    __syncthreads();
  }
  if (i < n) row_start[i + 1] = bsum[blockIdx.x] + buf[t];
  if (i == 0) row_start[0] = 0;
}

__global__ void scatter_edges(const void* __restrict__ ei, int E,
                              const int* __restrict__ row_start,
                              int* __restrict__ cursor, int* __restrict__ col_src,
                              const int* __restrict__ flags) {
  int e = blockIdx.x * blockDim.x + threadIdx.x;
  if (e >= E) return;
  int s, d;
  if (flags[1]) { s = loadI<true>(ei, e);  d = loadI<true>(ei, (size_t)E + e); }
  else          { s = loadI<false>(ei, e); d = loadI<false>(ei, (size_t)E + e); }
  int pos = atomicAdd(&cursor[d], 1);
  col_src[row_start[d] + pos] = s;
}

// ----------------- aggregation: gather + inline softmax weight -------------
// H=4 (round-14 proven body; w computed inline from L2-resident as/ad)
__global__ __launch_bounds__(256) void aggregate4(
    const unsigned short* __restrict__ h_in,   // [N][256] bf16 bits
    const float* __restrict__ wselfA,          // [N][4]
    const float* __restrict__ as_,             // [N][4]
    const float* __restrict__ ad_,             // [N][4]
    const int* __restrict__ row_start, const int* __restrict__ col_src,
    const void* __restrict__ bias,
    unsigned short* __restrict__ out,          // [N][256] bf16 bits
    int N, const int* __restrict__ flags) {
  const int dst = blockIdx.x * 4 + (threadIdx.x >> 6);
  if (dst >= N) return;
  const int l = threadIdx.x & 63;
  const int h = l >> 4;
  const int rs = row_start[dst];
  const int dg = row_start[dst + 1] - rs;
  const float ws = wselfA[dst * 4 + h];
  const float adv = ad_[dst * 4 + h];

  float a0, a1, a2, a3;
  {
    ushort4 sv = *(const ushort4*)(h_in + (size_t)dst * 256 + 4 * l);
    a0 = ws * bfbits2f(sv.x);
    a1 = ws * bfbits2f(sv.y);
    a2 = ws * bfbits2f(sv.z);
    a3 = ws * bfbits2f(sv.w);
  }
  float p = 0.f;
#pragma unroll 4
  for (int i = 0; i < dg; i++) {
    int sn = col_src[rs + i];
    float w = __expf(lrelu(as_[(size_t)sn * 4 + h] + adv));
    p += w;
    ushort4 sv = *(const ushort4*)(h_in + (size_t)sn * 256 + 4 * l);
    a0 += w * bfbits2f(sv.x);
    a1 += w * bfbits2f(sv.y);
    a2 += w * bfbits2f(sv.z);
    a3 += w * bfbits2f(sv.w);
  }
  const float inv = 1.0f / (p + ws + 1e-16f);
  const bool f = flags[0] != 0;
  float b0, b1, b2, b3;
  if (f) {
    b0 = loadF<true>(bias, 4 * l + 0); b1 = loadF<true>(bias, 4 * l + 1);
    b2 = loadF<true>(bias, 4 * l + 2); b3 = loadF<true>(bias, 4 * l + 3);
  } else {
    b0 = loadF<false>(bias, 4 * l + 0); b1 = loadF<false>(bias, 4 * l + 1);
    b2 = loadF<false>(bias, 4 * l + 2); b3 = loadF<false>(bias, 4 * l + 3);
  }
  float o0 = a0 * inv + b0, o1 = a1 * inv + b1;
  float o2 = a2 * inv + b2, o3 = a3 * inv + b3;
  o0 = o0 > 0.f ? o0 : __expf(o0) - 1.f;
  o1 = o1 > 0.f ? o1 : __expf(o1) - 1.f;
  o2 = o2 > 0.f ? o2 : __expf(o2) - 1.f;
  o3 = o3 > 0.f ? o3 : __expf(o3) - 1.f;
  ushort4 ov;
  ov.x = f2bfbits(o0); ov.y = f2bfbits(o1); ov.z = f2bfbits(o2); ov.w = f2bfbits(o3);
  *(ushort4*)(out + (size_t)dst * 256 + 4 * l) = ov;
}

// H=1: slot layout (round-14 proven body; w inline; p rides shfl reduction)
__global__ __launch_bounds__(256) void aggregate1(
    const unsigned short* __restrict__ h_in,   // [N][64] bf16 bits
    const float* __restrict__ wselfA,          // [N]
    const float* __restrict__ as_,             // [N]
    const float* __restrict__ ad_,             // [N]
    const int* __restrict__ row_start, const int* __restrict__ col_src,
    const void* __restrict__ bias,
    void* __restrict__ out, int N, const int* __restrict__ flags) {
  const int dst = blockIdx.x * 4 + (threadIdx.x >> 6);
  if (dst >= N) return;
  const int l = threadIdx.x & 63;
  const int el = l & 15;
  const int slot = l >> 4;
  const int rs = row_start[dst];
  const int dg = row_start[dst + 1] - rs;
  const float ws = wselfA[dst];
  const float adv = ad_[dst];

  float a0 = 0.f, a1 = 0.f, a2 = 0.f, a3 = 0.f, p = 0.f;
  if (slot == 0) {
    ushort4 sv = *(const ushort4*)(h_in + (size_t)dst * 64 + 4 * el);
    a0 = ws * bfbits2f(sv.x);
    a1 = ws * bfbits2f(sv.y);
    a2 = ws * bfbits2f(sv.z);
    a3 = ws * bfbits2f(sv.w);
  }
#pragma unroll 2
  for (int i = slot; i < dg; i += 4) {
    int sn = col_src[rs + i];
    float w = __expf(lrelu(as_[sn] + adv));
    p += w;
    ushort4 sv = *(const ushort4*)(h_in + (size_t)sn * 64 + 4 * el);
    a0 += w * bfbits2f(sv.x);
    a1 += w * bfbits2f(sv.y);
    a2 += w * bfbits2f(sv.z);
    a3 += w * bfbits2f(sv.w);
  }
  a0 += __shfl_xor(a0, 16); a0 += __shfl_xor(a0, 32);
  a1 += __shfl_xor(a1, 16); a1 += __shfl_xor(a1, 32);
  a2 += __shfl_xor(a2, 16); a2 += __shfl_xor(a2, 32);
  a3 += __shfl_xor(a3, 16); a3 += __shfl_xor(a3, 32);
  p  += __shfl_xor(p, 16);  p  += __shfl_xor(p, 32);

  if (slot == 0) {
    const float inv = 1.0f / (p + ws + 1e-16f);
    const bool f = flags[0] != 0;
    float b0, b1, b2, b3;
    if (f) {
      b0 = loadF<true>(bias, 4 * el + 0); b1 = loadF<true>(bias, 4 * el + 1);
      b2 = loadF<true>(bias, 4 * el + 2); b3 = loadF<true>(bias, 4 * el + 3);
    } else {
      b0 = loadF<false>(bias, 4 * el + 0); b1 = loadF<false>(bias, 4 * el + 1);
      b2 = loadF<false>(bias, 4 * el + 2); b3 = loadF<false>(bias, 4 * el + 3);
    }
    float o0 = a0 * inv + b0, o1 = a1 * inv + b1;
    float o2 = a2 * inv + b2, o3 = a3 * inv + b3;
    size_t ob = (size_t)dst * 64 + 4 * el;
    if (f) {
      ushort4 ov;
      ov.x = f2bfbits(o0); ov.y = f2bfbits(o1);
      ov.z = f2bfbits(o2); ov.w = f2bfbits(o3);
      *(ushort4*)((unsigned short*)out + ob) = ov;
    } else {
      float4 ov; ov.x = o0; ov.y = o1; ov.z = o2; ov.w = o3;
      *(float4*)((float*)out + ob) = ov;
    }
  }
}

// ---------------------------------------------------------------------------
extern "C" void kernel_launch(void* const* d_in, const int* in_sizes, int n_in,
                              void* d_out, int out_size, void* d_ws, size_t ws_size,
                              hipStream_t stream) {
  const void* x    = d_in[0];
  const void* ei   = d_in[1];
  const void* W1   = d_in[2];
  const void* as1w = d_in[3];
  const void* ad1w = d_in[4];
  const void* b1   = d_in[5];
  const void* W2   = d_in[6];
  const void* as2w = d_in[7];
  const void* ad2w = d_in[8];
  const void* b2   = d_in[9];

  const int N  = out_size / 64;      // 50000
  const int F  = in_sizes[0] / N;    // 128
  const int E  = in_sizes[1] / 2;    // 800000
  const int H1 = in_sizes[3] / 64;   // 4
  const int D1 = H1 * 64;            // 256
  const int D2 = 64;                 // layer-2 output dim (H2 = 1)

  size_t off = 0;
  auto alloc = [&](size_t bytes) -> void* {
    void* p = (char*)d_ws + off;
    off += (bytes + 255) & ~(size_t)255;
    return p;
  };
  int* flags = (int*)alloc(2 * sizeof(int));
  __hip_bfloat16* h1 = (__hip_bfloat16*)alloc((size_t)N * D1 * 2);
  __hip_bfloat16* x2 = (__hip_bfloat16*)alloc((size_t)N * D1 * 2);
  __hip_bfloat16* h2 = h1;  // h1 dead after layer-1 aggregate; reuse
  unsigned short* xb  = (unsigned short*)alloc((size_t)N * F * 2);   // x in bf16
  unsigned short* w1t = (unsigned short*)alloc((size_t)D1 * F * 2);  // [256][128]
  unsigned short* w2t = (unsigned short*)alloc((size_t)D2 * D1 * 2); // [64][256]
  float* as1 = (float*)alloc((size_t)N * H1 * 4);
  float* ad1 = (float*)alloc((size_t)N * H1 * 4);
  float* wself1 = (float*)alloc((size_t)N * H1 * 4);
  float* as2 = (float*)alloc((size_t)N * 4);
  float* ad2 = (float*)alloc((size_t)N * 4);
  float* wself2 = (float*)alloc((size_t)N * 4);
  int* zero_region = (int*)alloc((size_t)2 * N * 4);  // deg | cursor
  int* deg = zero_region;
  int* cursor = zero_region + N;
  int* row_start = (int*)alloc((size_t)(N + 1) * 4);
  int* col_src = (int*)alloc((size_t)E * 4);
  int* bsum = (int*)alloc((size_t)256 * 4);
  (void)ws_size; (void)n_in;

  const int nb = (N + 255) / 256;
  const int eb = (E + 255) / 256;
  const int db = (N + 3) / 4;
  const int gb = (N + 63) / 64;
  const int nzero = 2 * N;
  const int zb = (nzero + 255) / 256;

  // ---- dtype detection + zeroing (one dispatch) + CSR build + prep
  detect_zero<<<1 + zb, 256, 0, stream>>>((const uint32_t*)x, (const uint32_t*)ei,
                                          flags, zero_region, nzero);
  hist_kernel<<<eb, 256, 0, stream>>>(ei, E, deg, flags);
  scan_block_sums<<<nb, 256, 0, stream>>>(deg, bsum, N);
  scan_bsums<<<1, 256, 0, stream>>>(bsum, nb);
  scan_finalize<<<nb, 256, 0, stream>>>(deg, bsum, row_start, N);
  scatter_edges<<<eb, 256, 0, stream>>>(ei, E, row_start, cursor, col_src, flags);

  const size_t nx = (size_t)N * F;
  const int nb_cast = (int)((nx / 4 + 255) / 256);
  const int nb_t1 = (F * D1 + 255) / 256;
  const int nb_t2 = (D1 * D2 + 255) / 256;
  prep_all<<<nb_cast + nb_t1 + nb_t2, 256, 0, stream>>>(
      x, xb, nx, W1, w1t, F, D1, W2, w2t, D1, D2, nb_cast, nb_t1, flags);

  // ---- layer 1: GEMM 64x128 tiles (grid.y = 2), K=128 unrolled
  gemm_mfma_att<128, 8, 2><<<dim3(gb, 2), 256, 0, stream>>>(
      xb, w1t, (unsigned short*)h1, as1w, ad1w, as1, ad1, wself1, N, H1, flags);
  aggregate4<<<db, 256, 0, stream>>>((const unsigned short*)h1, wself1, as1, ad1,
                                     row_start, col_src, b1,
                                     (unsigned short*)x2, N, flags);

  // ---- layer 2: GEMM 64x64 tile, K=256 unrolled
  gemm_mfma_att<256, 4, 1><<<dim3(gb, 1), 256, 0, stream>>>(
      (const unsigned short*)x2, w2t, (unsigned short*)h2, as2w, ad2w,
      as2, ad2, wself2, N, 1, flags);
  aggregate1<<<db, 256, 0, stream>>>((const unsigned short*)h2, wself2, as2, ad2,
                                     row_start, col_src, b2, d_out, N, flags);
}

// Round 4
// 319.885 us; speedup vs baseline: 1.4281x; 1.0357x over previous
//
#include <hip/hip_runtime.h>
#include <hip/hip_bf16.h>
#include <stdint.h>

// ---------------------------------------------------------------------------
// 2-layer GAT (inference) on MI355X, dtype-adaptive.
// Round-18 changes vs round-17 (331.3 us):
//  * 3-stage prefix scan replaced by one-pass scan: block-local LDS scan +
//    atomicAdd(total) for the block base. Row segments are contiguous per dst
//    but block order is arbitrary; aggregates use deg[] for segment length.
//  * hist merged with prep (independent, both only need flags).
//  * scatter merged with gemm1 (scatter needs scan, gemm1 needs prep).
//    GEMM body factored into a __device__ function.
//  * When input x is already bf16, the x->xb cast is skipped entirely and
//    GEMM1 reads x directly (in-kernel pointer select on flags[0]).
//  Dispatch count 11 -> 7. aggregate bodies unchanged (66 us, 3.6 TB/s is
//  the measured fabric ceiling for this gather pattern).
// ---------------------------------------------------------------------------

typedef __attribute__((ext_vector_type(8))) short bf16x8;
typedef __attribute__((ext_vector_type(4))) float f32x4;

__device__ __forceinline__ float bf2f(__hip_bfloat16 v) { return __bfloat162float(v); }
__device__ __forceinline__ float bfbits2f(unsigned short s) {
  union { uint32_t u; float f; } v; v.u = ((uint32_t)s) << 16; return v.f;
}
__device__ __forceinline__ unsigned short f2bfbits(float f) {
  union { float f; uint32_t u; } v; v.f = f;
  uint32_t u = v.u;
  return (unsigned short)((u + 0x7fffu + ((u >> 16) & 1u)) >> 16);  // RNE
}

template <bool BF>
__device__ __forceinline__ float loadF(const void* p, size_t i) {
  if (BF) return bf2f(((const __hip_bfloat16*)p)[i]);
  return ((const float*)p)[i];
}
template <bool I64>
__device__ __forceinline__ int loadI(const void* p, size_t i) {
  if (I64) return (int)((const long long*)p)[i];
  return ((const int*)p)[i];
}
__device__ __forceinline__ float lrelu(float v) { return fmaxf(v, 0.2f * v); }

// ----------------- dtype detection + workspace zeroing ---------------------
__global__ __launch_bounds__(256) void detect_zero(
    const uint32_t* __restrict__ xbits, const uint32_t* __restrict__ eibits,
    int* __restrict__ flags, int* __restrict__ zero_region, int nzero) {
  if (blockIdx.x == 0) {
    if (threadIdx.x < 64) {
      const int l = threadIdx.x;
      uint32_t u = xbits[l];
      uint32_t e = (u >> 23) & 0xffu;
      bool plausible = (e < 160u && e > 90u) || (u & 0x7fffffffu) == 0u;
      unsigned long long m1 = __ballot(plausible);
      bool z = (eibits[2 * l + 1] == 0u);
      unsigned long long m2 = __ballot(z);
      if (l == 0) {
        flags[0] = (__popcll(m1) < 32) ? 1 : 0;  // 1 = floats are bf16
        flags[1] = (m2 == ~0ULL) ? 1 : 0;        // 1 = edge_index is int64
      }
    }
    return;
  }
  int i = (blockIdx.x - 1) * 256 + threadIdx.x;
  if (i < nzero) zero_region[i] = 0;
}

// ----------------- hist + prep (merged; both depend only on flags) ---------
__global__ __launch_bounds__(256) void hist_prep(
    const void* __restrict__ ei, int E, int* __restrict__ deg,
    const void* __restrict__ x, unsigned short* __restrict__ xb, size_t nx,
    const void* __restrict__ W1, unsigned short* __restrict__ w1t, int K1, int N1,
    const void* __restrict__ W2, unsigned short* __restrict__ w2t, int K2, int N2,
    int eb, int nb_cast, int nb_t1, const int* __restrict__ flags) {
  const int b = blockIdx.x;
  const bool f = flags[0] != 0;
  if (b < eb) {
    int e = b * 256 + threadIdx.x;
    if (e >= E) return;
    int d = flags[1] ? loadI<true>(ei, (size_t)E + e) : loadI<false>(ei, (size_t)E + e);
    atomicAdd(&deg[d], 1);
  } else if (b < eb + nb_cast) {
    if (f) return;  // bf16 input: GEMM1 reads x directly, no cast needed
    size_t i = ((size_t)(b - eb) * 256 + threadIdx.x) * 4;
    if (i >= nx) return;
    float4 v = *(const float4*)((const float*)x + i);
    ushort4 o;
    o.x = f2bfbits(v.x); o.y = f2bfbits(v.y);
    o.z = f2bfbits(v.z); o.w = f2bfbits(v.w);
    *(ushort4*)(xb + i) = o;
  } else if (b < eb + nb_cast + nb_t1) {
    int idx = (b - eb - nb_cast) * 256 + threadIdx.x;
    if (idx >= K1 * N1) return;
    int k = idx / N1, n = idx - k * N1;
    float v = f ? loadF<true>(W1, idx) : loadF<false>(W1, idx);
    w1t[(size_t)n * K1 + k] = f2bfbits(v);
  } else {
    int idx = (b - eb - nb_cast - nb_t1) * 256 + threadIdx.x;
    if (idx >= K2 * N2) return;
    int k = idx / N2, n = idx - k * N2;
    float v = f ? loadF<true>(W2, idx) : loadF<false>(W2, idx);
    w2t[(size_t)n * K2 + k] = f2bfbits(v);
  }
}

// ----------------- one-pass scan: block-local scan + atomic base -----------
// row_start[i] is a valid exclusive offset for row i's contiguous segment;
// block order (hence segment order in col_src) is arbitrary. deg[] supplies
// segment lengths downstream.
__global__ __launch_bounds__(256) void scan_onepass(
    const int* __restrict__ deg, int* __restrict__ row_start,
    int* __restrict__ total, int n) {
  __shared__ int buf[256];
  __shared__ int sbase;
  const int t = threadIdx.x;
  const int i = blockIdx.x * 256 + t;
  int v = (i < n) ? deg[i] : 0;
  buf[t] = v;
  __syncthreads();
  for (int o = 1; o < 256; o <<= 1) {
    int x = (t >= o) ? buf[t - o] : 0;
    __syncthreads();
    buf[t] += x;
    __syncthreads();
  }
  if (t == 255) sbase = atomicAdd(total, buf[255]);
  __syncthreads();
  if (i < n) row_start[i] = sbase + buf[t] - v;  // exclusive within block
}

// ----------------- MFMA GEMM + fused attention-dot epilogue (device) -------
template <int KC, int NT, int HB>
__device__ __forceinline__ void gemm_body(
    int bx, int by, int tid,
    const unsigned short* __restrict__ A,   // [M][KC] bf16 bits
    const unsigned short* __restrict__ BT,  // [Htot*64][KC] bf16 bits
    unsigned short* __restrict__ C,         // [M][Htot*64] bf16 bits
    const void* __restrict__ att_s, const void* __restrict__ att_d,
    float* __restrict__ as_o, float* __restrict__ ad_o,
    float* __restrict__ wself_o,
    int M, int Htot, bool f) {
  const int lane = tid & 63;
  const int col = lane & 15;
  const int quad = lane >> 4;
  const int m0 = bx * 64 + (tid >> 6) * 16;
  const int n0 = by * (NT * 16);
  const int NCOL = Htot * 64;

  int gm = m0 + col;                 // A row this lane supplies
  if (gm > M - 1) gm = M - 1;        // clamp: garbage only affects guarded rows
  const unsigned short* arow = A + (size_t)gm * KC + quad * 8;
  const unsigned short* bbase = BT + (size_t)(n0 + col) * KC + quad * 8;

  f32x4 acc[NT] = {};
#pragma unroll
  for (int k0 = 0; k0 < KC; k0 += 32) {
    bf16x8 a = *(const bf16x8*)(arow + k0);
#pragma unroll
    for (int s = 0; s < NT; s++) {
      bf16x8 b = *(const bf16x8*)(bbase + (size_t)s * 16 * KC + k0);
      acc[s] = __builtin_amdgcn_mfma_f32_16x16x32_bf16(a, b, acc[s], 0, 0, 0);
    }
  }
  // store C
#pragma unroll
  for (int s = 0; s < NT; s++)
#pragma unroll
    for (int r = 0; r < 4; r++) {
      int m = m0 + quad * 4 + r;
      if (m < M) C[(size_t)m * NCOL + n0 + s * 16 + col] = f2bfbits(acc[s][r]);
    }
  // fused attention dots: head h covers s in [h*SC, (h+1)*SC)
  const int SC = NT / HB;
#pragma unroll
  for (int h = 0; h < HB; h++) {
    const int gh = by * HB + h;
    float ps[4] = {0.f, 0.f, 0.f, 0.f};
    float pd[4] = {0.f, 0.f, 0.f, 0.f};
#pragma unroll
    for (int j = 0; j < SC; j++) {
      int s = h * SC + j;
      int ci = gh * 64 + j * 16 + col;
      float av = f ? loadF<true>(att_s, ci) : loadF<false>(att_s, ci);
      float dv = f ? loadF<true>(att_d, ci) : loadF<false>(att_d, ci);
#pragma unroll
      for (int r = 0; r < 4; r++) {
        ps[r] += acc[s][r] * av;
        pd[r] += acc[s][r] * dv;
      }
    }
#pragma unroll
    for (int o = 1; o < 16; o <<= 1) {
#pragma unroll
      for (int r = 0; r < 4; r++) {
        ps[r] += __shfl_xor(ps[r], o);
        pd[r] += __shfl_xor(pd[r], o);
      }
    }
    if (col == 0) {
#pragma unroll
      for (int r = 0; r < 4; r++) {
        int m = m0 + quad * 4 + r;
        if (m < M) {
          as_o[m * Htot + gh] = ps[r];
          ad_o[m * Htot + gh] = pd[r];
          wself_o[m * Htot + gh] = __expf(lrelu(ps[r] + pd[r]));  // no max-sub
        }
      }
    }
  }
}

// ----------------- scatter + GEMM1 (merged; independent work) --------------
__global__ __launch_bounds__(256, 4) void scatter_gemm1(
    const void* __restrict__ ei, int E, const int* __restrict__ row_start,
    int* __restrict__ cursor, int* __restrict__ col_src,
    int eb, int gb,
    const unsigned short* __restrict__ xb, const void* __restrict__ x,
    const unsigned short* __restrict__ w1t,
    unsigned short* __restrict__ C,
    const void* __restrict__ att_s, const void* __restrict__ att_d,
    float* __restrict__ as_o, float* __restrict__ ad_o,
    float* __restrict__ wself_o,
    int M, int Htot, const int* __restrict__ flags) {
  const int b = blockIdx.x;
  if (b < eb) {
    int e = b * 256 + threadIdx.x;
    if (e >= E) return;
    int s, d;
    if (flags[1]) { s = loadI<true>(ei, e);  d = loadI<true>(ei, (size_t)E + e); }
    else          { s = loadI<false>(ei, e); d = loadI<false>(ei, (size_t)E + e); }
    int pos = atomicAdd(&cursor[d], 1);
    col_src[row_start[d] + pos] = s;
  } else {
    const int bb = b - eb;
    const int bx = bb % gb, by = bb / gb;
    const bool f = flags[0] != 0;
    const unsigned short* Ap = f ? (const unsigned short*)x : xb;
    gemm_body<128, 8, 2>(bx, by, threadIdx.x, Ap, w1t, C, att_s, att_d,
                         as_o, ad_o, wself_o, M, Htot, f);
  }
}

// ----------------- standalone GEMM (layer 2) -------------------------------
template <int KC, int NT, int HB>
__global__ __launch_bounds__(256, 4) void gemm_kernel(
    const unsigned short* __restrict__ A, const unsigned short* __restrict__ BT,
    unsigned short* __restrict__ C,
    const void* __restrict__ att_s, const void* __restrict__ att_d,
    float* __restrict__ as_o, float* __restrict__ ad_o,
    float* __restrict__ wself_o,
    int M, int Htot, const int* __restrict__ flags) {
  gemm_body<KC, NT, HB>(blockIdx.x, blockIdx.y, threadIdx.x, A, BT, C,
                        att_s, att_d, as_o, ad_o, wself_o, M, Htot,
                        flags[0] != 0);
}

// ----------------- aggregation: gather + inline softmax weight -------------
// H=4 (proven body; w computed inline from L2-resident as/ad; deg[] length)
__global__ __launch_bounds__(256) void aggregate4(
    const unsigned short* __restrict__ h_in,   // [N][256] bf16 bits
    const float* __restrict__ wselfA,          // [N][4]
    const float* __restrict__ as_,             // [N][4]
    const float* __restrict__ ad_,             // [N][4]
    const int* __restrict__ row_start, const int* __restrict__ deg,
    const int* __restrict__ col_src,
    const void* __restrict__ bias,
    unsigned short* __restrict__ out,          // [N][256] bf16 bits
    int N, const int* __restrict__ flags) {
  const int dst = blockIdx.x * 4 + (threadIdx.x >> 6);
  if (dst >= N) return;
  const int l = threadIdx.x & 63;
  const int h = l >> 4;
  const int rs = row_start[dst];
  const int dg = deg[dst];
  const float ws = wselfA[dst * 4 + h];
  const float adv = ad_[dst * 4 + h];

  float a0, a1, a2, a3;
  {
    ushort4 sv = *(const ushort4*)(h_in + (size_t)dst * 256 + 4 * l);
    a0 = ws * bfbits2f(sv.x);
    a1 = ws * bfbits2f(sv.y);
    a2 = ws * bfbits2f(sv.z);
    a3 = ws * bfbits2f(sv.w);
  }
  float p = 0.f;
#pragma unroll 4
  for (int i = 0; i < dg; i++) {
    int sn = col_src[rs + i];
    float w = __expf(lrelu(as_[(size_t)sn * 4 + h] + adv));
    p += w;
    ushort4 sv = *(const ushort4*)(h_in + (size_t)sn * 256 + 4 * l);
    a0 += w * bfbits2f(sv.x);
    a1 += w * bfbits2f(sv.y);
    a2 += w * bfbits2f(sv.z);
    a3 += w * bfbits2f(sv.w);
  }
  const float inv = 1.0f / (p + ws + 1e-16f);
  const bool f = flags[0] != 0;
  float b0, b1, b2, b3;
  if (f) {
    b0 = loadF<true>(bias, 4 * l + 0); b1 = loadF<true>(bias, 4 * l + 1);
    b2 = loadF<true>(bias, 4 * l + 2); b3 = loadF<true>(bias, 4 * l + 3);
  } else {
    b0 = loadF<false>(bias, 4 * l + 0); b1 = loadF<false>(bias, 4 * l + 1);
    b2 = loadF<false>(bias, 4 * l + 2); b3 = loadF<false>(bias, 4 * l + 3);
  }
  float o0 = a0 * inv + b0, o1 = a1 * inv + b1;
  float o2 = a2 * inv + b2, o3 = a3 * inv + b3;
  o0 = o0 > 0.f ? o0 : __expf(o0) - 1.f;
  o1 = o1 > 0.f ? o1 : __expf(o1) - 1.f;
  o2 = o2 > 0.f ? o2 : __expf(o2) - 1.f;
  o3 = o3 > 0.f ? o3 : __expf(o3) - 1.f;
  ushort4 ov;
  ov.x = f2bfbits(o0); ov.y = f2bfbits(o1); ov.z = f2bfbits(o2); ov.w = f2bfbits(o3);
  *(ushort4*)(out + (size_t)dst * 256 + 4 * l) = ov;
}

// H=1: slot layout (proven body; w inline; p rides shfl reduction)
__global__ __launch_bounds__(256) void aggregate1(
    const unsigned short* __restrict__ h_in,   // [N][64] bf16 bits
    const float* __restrict__ wselfA,          // [N]
    const float* __restrict__ as_,             // [N]
    const float* __restrict__ ad_,             // [N]
    const int* __restrict__ row_start, const int* __restrict__ deg,
    const int* __restrict__ col_src,
    const void* __restrict__ bias,
    void* __restrict__ out, int N, const int* __restrict__ flags) {
  const int dst = blockIdx.x * 4 + (threadIdx.x >> 6);
  if (dst >= N) return;
  const int l = threadIdx.x & 63;
  const int el = l & 15;
  const int slot = l >> 4;
  const int rs = row_start[dst];
  const int dg = deg[dst];
  const float ws = wselfA[dst];
  const float adv = ad_[dst];

  float a0 = 0.f, a1 = 0.f, a2 = 0.f, a3 = 0.f, p = 0.f;
  if (slot == 0) {
    ushort4 sv = *(const ushort4*)(h_in + (size_t)dst * 64 + 4 * el);
    a0 = ws * bfbits2f(sv.x);
    a1 = ws * bfbits2f(sv.y);
    a2 = ws * bfbits2f(sv.z);
    a3 = ws * bfbits2f(sv.w);
  }
#pragma unroll 2
  for (int i = slot; i < dg; i += 4) {
    int sn = col_src[rs + i];
    float w = __expf(lrelu(as_[sn] + adv));
    p += w;
    ushort4 sv = *(const ushort4*)(h_in + (size_t)sn * 64 + 4 * el);
    a0 += w * bfbits2f(sv.x);
    a1 += w * bfbits2f(sv.y);
    a2 += w * bfbits2f(sv.z);
    a3 += w * bfbits2f(sv.w);
  }
  a0 += __shfl_xor(a0, 16); a0 += __shfl_xor(a0, 32);
  a1 += __shfl_xor(a1, 16); a1 += __shfl_xor(a1, 32);
  a2 += __shfl_xor(a2, 16); a2 += __shfl_xor(a2, 32);
  a3 += __shfl_xor(a3, 16); a3 += __shfl_xor(a3, 32);
  p  += __shfl_xor(p, 16);  p  += __shfl_xor(p, 32);

  if (slot == 0) {
    const float inv = 1.0f / (p + ws + 1e-16f);
    const bool f = flags[0] != 0;
    float b0, b1, b2, b3;
    if (f) {
      b0 = loadF<true>(bias, 4 * el + 0); b1 = loadF<true>(bias, 4 * el + 1);
      b2 = loadF<true>(bias, 4 * el + 2); b3 = loadF<true>(bias, 4 * el + 3);
    } else {
      b0 = loadF<false>(bias, 4 * el + 0); b1 = loadF<false>(bias, 4 * el + 1);
      b2 = loadF<false>(bias, 4 * el + 2); b3 = loadF<false>(bias, 4 * el + 3);
    }
    float o0 = a0 * inv + b0, o1 = a1 * inv + b1;
    float o2 = a2 * inv + b2, o3 = a3 * inv + b3;
    size_t ob = (size_t)dst * 64 + 4 * el;
    if (f) {
      ushort4 ov;
      ov.x = f2bfbits(o0); ov.y = f2bfbits(o1);
      ov.z = f2bfbits(o2); ov.w = f2bfbits(o3);
      *(ushort4*)((unsigned short*)out + ob) = ov;
    } else {
      float4 ov; ov.x = o0; ov.y = o1; ov.z = o2; ov.w = o3;
      *(float4*)((float*)out + ob) = ov;
    }
  }
}

// ---------------------------------------------------------------------------
extern "C" void kernel_launch(void* const* d_in, const int* in_sizes, int n_in,
                              void* d_out, int out_size, void* d_ws, size_t ws_size,
                              hipStream_t stream) {
  const void* x    = d_in[0];
  const void* ei   = d_in[1];
  const void* W1   = d_in[2];
  const void* as1w = d_in[3];
  const void* ad1w = d_in[4];
  const void* b1   = d_in[5];
  const void* W2   = d_in[6];
  const void* as2w = d_in[7];
  const void* ad2w = d_in[8];
  const void* b2   = d_in[9];

  const int N  = out_size / 64;      // 50000
  const int F  = in_sizes[0] / N;    // 128
  const int E  = in_sizes[1] / 2;    // 800000
  const int H1 = in_sizes[3] / 64;   // 4
  const int D1 = H1 * 64;            // 256
  const int D2 = 64;                 // layer-2 output dim (H2 = 1)

  size_t off = 0;
  auto alloc = [&](size_t bytes) -> void* {
    void* p = (char*)d_ws + off;
    off += (bytes + 255) & ~(size_t)255;
    return p;
  };
  int* flags = (int*)alloc(2 * sizeof(int));
  __hip_bfloat16* h1 = (__hip_bfloat16*)alloc((size_t)N * D1 * 2);
  __hip_bfloat16* x2 = (__hip_bfloat16*)alloc((size_t)N * D1 * 2);
  __hip_bfloat16* h2 = h1;  // h1 dead after layer-1 aggregate; reuse
  unsigned short* xb  = (unsigned short*)alloc((size_t)N * F * 2);   // x in bf16
  unsigned short* w1t = (unsigned short*)alloc((size_t)D1 * F * 2);  // [256][128]
  unsigned short* w2t = (unsigned short*)alloc((size_t)D2 * D1 * 2); // [64][256]
  float* as1 = (float*)alloc((size_t)N * H1 * 4);
  float* ad1 = (float*)alloc((size_t)N * H1 * 4);
  float* wself1 = (float*)alloc((size_t)N * H1 * 4);
  float* as2 = (float*)alloc((size_t)N * 4);
  float* ad2 = (float*)alloc((size_t)N * 4);
  float* wself2 = (float*)alloc((size_t)N * 4);
  int* zero_region = (int*)alloc((size_t)(2 * N + 64) * 4);  // deg | cursor | total
  int* deg = zero_region;
  int* cursor = zero_region + N;
  int* total = zero_region + 2 * N;
  int* row_start = (int*)alloc((size_t)(N + 1) * 4);
  int* col_src = (int*)alloc((size_t)E * 4);
  (void)ws_size; (void)n_in;

  const int nb = (N + 255) / 256;
  const int eb = (E + 255) / 256;
  const int db = (N + 3) / 4;
  const int gb = (N + 63) / 64;
  const int nzero = 2 * N + 64;
  const int zb = (nzero + 255) / 256;

  const size_t nx = (size_t)N * F;
  const int nb_cast = (int)((nx / 4 + 255) / 256);
  const int nb_t1 = (F * D1 + 255) / 256;
  const int nb_t2 = (D1 * D2 + 255) / 256;

  // 1. dtype detection + zeroing
  detect_zero<<<1 + zb, 256, 0, stream>>>((const uint32_t*)x, (const uint32_t*)ei,
                                          flags, zero_region, nzero);
  // 2. hist || prep (cast skipped when bf16)
  hist_prep<<<eb + nb_cast + nb_t1 + nb_t2, 256, 0, stream>>>(
      ei, E, deg, x, xb, nx, W1, w1t, F, D1, W2, w2t, D1, D2,
      eb, nb_cast, nb_t1, flags);
  // 3. one-pass scan
  scan_onepass<<<nb, 256, 0, stream>>>(deg, row_start, total, N);
  // 4. scatter || GEMM1 (64x128 tiles; flattened 2D: gb x 2)
  scatter_gemm1<<<eb + gb * 2, 256, 0, stream>>>(
      ei, E, row_start, cursor, col_src, eb, gb,
      xb, x, w1t, (unsigned short*)h1, as1w, ad1w, as1, ad1, wself1, N, H1, flags);
  // 5. layer-1 aggregate (inline softmax weights)
  aggregate4<<<db, 256, 0, stream>>>((const unsigned short*)h1, wself1, as1, ad1,
                                     row_start, deg, col_src, b1,
                                     (unsigned short*)x2, N, flags);
  // 6. layer-2 GEMM 64x64 tile, K=256 unrolled
  gemm_kernel<256, 4, 1><<<dim3(gb, 1), 256, 0, stream>>>(
      (const unsigned short*)x2, w2t, (unsigned short*)h2, as2w, ad2w,
      as2, ad2, wself2, N, 1, flags);
  // 7. layer-2 aggregate
  aggregate1<<<db, 256, 0, stream>>>((const unsigned short*)h2, wself2, as2, ad2,
                                     row_start, deg, col_src, b2, d_out, N, flags);
}

// Round 5
// 293.192 us; speedup vs baseline: 1.5581x; 1.0910x over previous
//
#include <hip/hip_runtime.h>
#include <hip/hip_bf16.h>
#include <stdint.h>

// ---------------------------------------------------------------------------
// 2-layer GAT (inference) on MI355X, dtype-adaptive.
// Round-19 changes vs round-18 (319.9 us):
//  * Scatter made atomic-free: hist's atomicAdd(&deg[d],1) return value IS
//    the within-row position -> saved to ppos[e] (coalesced). The scatter
//    branch of scatter_gemm1 now does one independent scattered store
//    col_src[row_start[d]+ppos[e]] = s with no cursor atomic and no
//    dependent address chain (was: device-scope atomic round-trip -> store,
//    ~60 us of the 81 us merged kernel, all pipes idle).
//  * cursor array deleted; zero region halves to deg|total.
//  Everything else byte-identical to round 18.
// ---------------------------------------------------------------------------

typedef __attribute__((ext_vector_type(8))) short bf16x8;
typedef __attribute__((ext_vector_type(4))) float f32x4;

__device__ __forceinline__ float bf2f(__hip_bfloat16 v) { return __bfloat162float(v); }
__device__ __forceinline__ float bfbits2f(unsigned short s) {
  union { uint32_t u; float f; } v; v.u = ((uint32_t)s) << 16; return v.f;
}
__device__ __forceinline__ unsigned short f2bfbits(float f) {
  union { float f; uint32_t u; } v; v.f = f;
  uint32_t u = v.u;
  return (unsigned short)((u + 0x7fffu + ((u >> 16) & 1u)) >> 16);  // RNE
}

template <bool BF>
__device__ __forceinline__ float loadF(const void* p, size_t i) {
  if (BF) return bf2f(((const __hip_bfloat16*)p)[i]);
  return ((const float*)p)[i];
}
template <bool I64>
__device__ __forceinline__ int loadI(const void* p, size_t i) {
  if (I64) return (int)((const long long*)p)[i];
  return ((const int*)p)[i];
}
__device__ __forceinline__ float lrelu(float v) { return fmaxf(v, 0.2f * v); }

// ----------------- dtype detection + workspace zeroing ---------------------
__global__ __launch_bounds__(256) void detect_zero(
    const uint32_t* __restrict__ xbits, const uint32_t* __restrict__ eibits,
    int* __restrict__ flags, int* __restrict__ zero_region, int nzero) {
  if (blockIdx.x == 0) {
    if (threadIdx.x < 64) {
      const int l = threadIdx.x;
      uint32_t u = xbits[l];
      uint32_t e = (u >> 23) & 0xffu;
      bool plausible = (e < 160u && e > 90u) || (u & 0x7fffffffu) == 0u;
      unsigned long long m1 = __ballot(plausible);
      bool z = (eibits[2 * l + 1] == 0u);
      unsigned long long m2 = __ballot(z);
      if (l == 0) {
        flags[0] = (__popcll(m1) < 32) ? 1 : 0;  // 1 = floats are bf16
        flags[1] = (m2 == ~0ULL) ? 1 : 0;        // 1 = edge_index is int64
      }
    }
    return;
  }
  int i = (blockIdx.x - 1) * 256 + threadIdx.x;
  if (i < nzero) zero_region[i] = 0;
}

// ----------------- hist + prep (merged; both depend only on flags) ---------
// hist also records ppos[e] = within-row position (atomicAdd return value),
// making the later scatter atomic-free.
__global__ __launch_bounds__(256) void hist_prep(
    const void* __restrict__ ei, int E, int* __restrict__ deg,
    int* __restrict__ ppos,
    const void* __restrict__ x, unsigned short* __restrict__ xb, size_t nx,
    const void* __restrict__ W1, unsigned short* __restrict__ w1t, int K1, int N1,
    const void* __restrict__ W2, unsigned short* __restrict__ w2t, int K2, int N2,
    int eb, int nb_cast, int nb_t1, const int* __restrict__ flags) {
  const int b = blockIdx.x;
  const bool f = flags[0] != 0;
  if (b < eb) {
    int e = b * 256 + threadIdx.x;
    if (e >= E) return;
    int d = flags[1] ? loadI<true>(ei, (size_t)E + e) : loadI<false>(ei, (size_t)E + e);
    ppos[e] = atomicAdd(&deg[d], 1);
  } else if (b < eb + nb_cast) {
    if (f) return;  // bf16 input: GEMM1 reads x directly, no cast needed
    size_t i = ((size_t)(b - eb) * 256 + threadIdx.x) * 4;
    if (i >= nx) return;
    float4 v = *(const float4*)((const float*)x + i);
    ushort4 o;
    o.x = f2bfbits(v.x); o.y = f2bfbits(v.y);
    o.z = f2bfbits(v.z); o.w = f2bfbits(v.w);
    *(ushort4*)(xb + i) = o;
  } else if (b < eb + nb_cast + nb_t1) {
    int idx = (b - eb - nb_cast) * 256 + threadIdx.x;
    if (idx >= K1 * N1) return;
    int k = idx / N1, n = idx - k * N1;
    float v = f ? loadF<true>(W1, idx) : loadF<false>(W1, idx);
    w1t[(size_t)n * K1 + k] = f2bfbits(v);
  } else {
    int idx = (b - eb - nb_cast - nb_t1) * 256 + threadIdx.x;
    if (idx >= K2 * N2) return;
    int k = idx / N2, n = idx - k * N2;
    float v = f ? loadF<true>(W2, idx) : loadF<false>(W2, idx);
    w2t[(size_t)n * K2 + k] = f2bfbits(v);
  }
}

// ----------------- one-pass scan: block-local scan + atomic base -----------
__global__ __launch_bounds__(256) void scan_onepass(
    const int* __restrict__ deg, int* __restrict__ row_start,
    int* __restrict__ total, int n) {
  __shared__ int buf[256];
  __shared__ int sbase;
  const int t = threadIdx.x;
  const int i = blockIdx.x * 256 + t;
  int v = (i < n) ? deg[i] : 0;
  buf[t] = v;
  __syncthreads();
  for (int o = 1; o < 256; o <<= 1) {
    int x = (t >= o) ? buf[t - o] : 0;
    __syncthreads();
    buf[t] += x;
    __syncthreads();
  }
  if (t == 255) sbase = atomicAdd(total, buf[255]);
  __syncthreads();
  if (i < n) row_start[i] = sbase + buf[t] - v;  // exclusive within block
}

// ----------------- MFMA GEMM + fused attention-dot epilogue (device) -------
template <int KC, int NT, int HB>
__device__ __forceinline__ void gemm_body(
    int bx, int by, int tid,
    const unsigned short* __restrict__ A,   // [M][KC] bf16 bits
    const unsigned short* __restrict__ BT,  // [Htot*64][KC] bf16 bits
    unsigned short* __restrict__ C,         // [M][Htot*64] bf16 bits
    const void* __restrict__ att_s, const void* __restrict__ att_d,
    float* __restrict__ as_o, float* __restrict__ ad_o,
    float* __restrict__ wself_o,
    int M, int Htot, bool f) {
  const int lane = tid & 63;
  const int col = lane & 15;
  const int quad = lane >> 4;
  const int m0 = bx * 64 + (tid >> 6) * 16;
  const int n0 = by * (NT * 16);
  const int NCOL = Htot * 64;

  int gm = m0 + col;                 // A row this lane supplies
  if (gm > M - 1) gm = M - 1;        // clamp: garbage only affects guarded rows
  const unsigned short* arow = A + (size_t)gm * KC + quad * 8;
  const unsigned short* bbase = BT + (size_t)(n0 + col) * KC + quad * 8;

  f32x4 acc[NT] = {};
#pragma unroll
  for (int k0 = 0; k0 < KC; k0 += 32) {
    bf16x8 a = *(const bf16x8*)(arow + k0);
#pragma unroll
    for (int s = 0; s < NT; s++) {
      bf16x8 b = *(const bf16x8*)(bbase + (size_t)s * 16 * KC + k0);
      acc[s] = __builtin_amdgcn_mfma_f32_16x16x32_bf16(a, b, acc[s], 0, 0, 0);
    }
  }
  // store C
#pragma unroll
  for (int s = 0; s < NT; s++)
#pragma unroll
    for (int r = 0; r < 4; r++) {
      int m = m0 + quad * 4 + r;
      if (m < M) C[(size_t)m * NCOL + n0 + s * 16 + col] = f2bfbits(acc[s][r]);
    }
  // fused attention dots: head h covers s in [h*SC, (h+1)*SC)
  const int SC = NT / HB;
#pragma unroll
  for (int h = 0; h < HB; h++) {
    const int gh = by * HB + h;
    float ps[4] = {0.f, 0.f, 0.f, 0.f};
    float pd[4] = {0.f, 0.f, 0.f, 0.f};
#pragma unroll
    for (int j = 0; j < SC; j++) {
      int s = h * SC + j;
      int ci = gh * 64 + j * 16 + col;
      float av = f ? loadF<true>(att_s, ci) : loadF<false>(att_s, ci);
      float dv = f ? loadF<true>(att_d, ci) : loadF<false>(att_d, ci);
#pragma unroll
      for (int r = 0; r < 4; r++) {
        ps[r] += acc[s][r] * av;
        pd[r] += acc[s][r] * dv;
      }
    }
#pragma unroll
    for (int o = 1; o < 16; o <<= 1) {
#pragma unroll
      for (int r = 0; r < 4; r++) {
        ps[r] += __shfl_xor(ps[r], o);
        pd[r] += __shfl_xor(pd[r], o);
      }
    }
    if (col == 0) {
#pragma unroll
      for (int r = 0; r < 4; r++) {
        int m = m0 + quad * 4 + r;
        if (m < M) {
          as_o[m * Htot + gh] = ps[r];
          ad_o[m * Htot + gh] = pd[r];
          wself_o[m * Htot + gh] = __expf(lrelu(ps[r] + pd[r]));  // no max-sub
        }
      }
    }
  }
}

// ----------------- scatter + GEMM1 (merged; independent work) --------------
// Scatter is atomic-free: position comes from ppos[] recorded during hist.
__global__ __launch_bounds__(256, 4) void scatter_gemm1(
    const void* __restrict__ ei, int E, const int* __restrict__ row_start,
    const int* __restrict__ ppos, int* __restrict__ col_src,
    int eb, int gb,
    const unsigned short* __restrict__ xb, const void* __restrict__ x,
    const unsigned short* __restrict__ w1t,
    unsigned short* __restrict__ C,
    const void* __restrict__ att_s, const void* __restrict__ att_d,
    float* __restrict__ as_o, float* __restrict__ ad_o,
    float* __restrict__ wself_o,
    int M, int Htot, const int* __restrict__ flags) {
  const int b = blockIdx.x;
  if (b < eb) {
    int e = b * 256 + threadIdx.x;
    if (e >= E) return;
    int s, d;
    if (flags[1]) { s = loadI<true>(ei, e);  d = loadI<true>(ei, (size_t)E + e); }
    else          { s = loadI<false>(ei, e); d = loadI<false>(ei, (size_t)E + e); }
    col_src[row_start[d] + ppos[e]] = s;
  } else {
    const int bb = b - eb;
    const int bx = bb % gb, by = bb / gb;
    const bool f = flags[0] != 0;
    const unsigned short* Ap = f ? (const unsigned short*)x : xb;
    gemm_body<128, 8, 2>(bx, by, threadIdx.x, Ap, w1t, C, att_s, att_d,
                         as_o, ad_o, wself_o, M, Htot, f);
  }
}

// ----------------- standalone GEMM (layer 2) -------------------------------
template <int KC, int NT, int HB>
__global__ __launch_bounds__(256, 4) void gemm_kernel(
    const unsigned short* __restrict__ A, const unsigned short* __restrict__ BT,
    unsigned short* __restrict__ C,
    const void* __restrict__ att_s, const void* __restrict__ att_d,
    float* __restrict__ as_o, float* __restrict__ ad_o,
    float* __restrict__ wself_o,
    int M, int Htot, const int* __restrict__ flags) {
  gemm_body<KC, NT, HB>(blockIdx.x, blockIdx.y, threadIdx.x, A, BT, C,
                        att_s, att_d, as_o, ad_o, wself_o, M, Htot,
                        flags[0] != 0);
}

// ----------------- aggregation: gather + inline softmax weight -------------
// H=4 (proven body; w computed inline from L2-resident as/ad; deg[] length)
__global__ __launch_bounds__(256) void aggregate4(
    const unsigned short* __restrict__ h_in,   // [N][256] bf16 bits
    const float* __restrict__ wselfA,          // [N][4]
    const float* __restrict__ as_,             // [N][4]
    const float* __restrict__ ad_,             // [N][4]
    const int* __restrict__ row_start, const int* __restrict__ deg,
    const int* __restrict__ col_src,
    const void* __restrict__ bias,
    unsigned short* __restrict__ out,          // [N][256] bf16 bits
    int N, const int* __restrict__ flags) {
  const int dst = blockIdx.x * 4 + (threadIdx.x >> 6);
  if (dst >= N) return;
  const int l = threadIdx.x & 63;
  const int h = l >> 4;
  const int rs = row_start[dst];
  const int dg = deg[dst];
  const float ws = wselfA[dst * 4 + h];
  const float adv = ad_[dst * 4 + h];

  float a0, a1, a2, a3;
  {
    ushort4 sv = *(const ushort4*)(h_in + (size_t)dst * 256 + 4 * l);
    a0 = ws * bfbits2f(sv.x);
    a1 = ws * bfbits2f(sv.y);
    a2 = ws * bfbits2f(sv.z);
    a3 = ws * bfbits2f(sv.w);
  }
  float p = 0.f;
#pragma unroll 4
  for (int i = 0; i < dg; i++) {
    int sn = col_src[rs + i];
    float w = __expf(lrelu(as_[(size_t)sn * 4 + h] + adv));
    p += w;
    ushort4 sv = *(const ushort4*)(h_in + (size_t)sn * 256 + 4 * l);
    a0 += w * bfbits2f(sv.x);
    a1 += w * bfbits2f(sv.y);
    a2 += w * bfbits2f(sv.z);
    a3 += w * bfbits2f(sv.w);
  }
  const float inv = 1.0f / (p + ws + 1e-16f);
  const bool f = flags[0] != 0;
  float b0, b1, b2, b3;
  if (f) {
    b0 = loadF<true>(bias, 4 * l + 0); b1 = loadF<true>(bias, 4 * l + 1);
    b2 = loadF<true>(bias, 4 * l + 2); b3 = loadF<true>(bias, 4 * l + 3);
  } else {
    b0 = loadF<false>(bias, 4 * l + 0); b1 = loadF<false>(bias, 4 * l + 1);
    b2 = loadF<false>(bias, 4 * l + 2); b3 = loadF<false>(bias, 4 * l + 3);
  }
  float o0 = a0 * inv + b0, o1 = a1 * inv + b1;
  float o2 = a2 * inv + b2, o3 = a3 * inv + b3;
  o0 = o0 > 0.f ? o0 : __expf(o0) - 1.f;
  o1 = o1 > 0.f ? o1 : __expf(o1) - 1.f;
  o2 = o2 > 0.f ? o2 : __expf(o2) - 1.f;
  o3 = o3 > 0.f ? o3 : __expf(o3) - 1.f;
  ushort4 ov;
  ov.x = f2bfbits(o0); ov.y = f2bfbits(o1); ov.z = f2bfbits(o2); ov.w = f2bfbits(o3);
  *(ushort4*)(out + (size_t)dst * 256 + 4 * l) = ov;
}

// H=1: slot layout (proven body; w inline; p rides shfl reduction)
__global__ __launch_bounds__(256) void aggregate1(
    const unsigned short* __restrict__ h_in,   // [N][64] bf16 bits
    const float* __restrict__ wselfA,          // [N]
    const float* __restrict__ as_,             // [N]
    const float* __restrict__ ad_,             // [N]
    const int* __restrict__ row_start, const int* __restrict__ deg,
    const int* __restrict__ col_src,
    const void* __restrict__ bias,
    void* __restrict__ out, int N, const int* __restrict__ flags) {
  const int dst = blockIdx.x * 4 + (threadIdx.x >> 6);
  if (dst >= N) return;
  const int l = threadIdx.x & 63;
  const int el = l & 15;
  const int slot = l >> 4;
  const int rs = row_start[dst];
  const int dg = deg[dst];
  const float ws = wselfA[dst];
  const float adv = ad_[dst];

  float a0 = 0.f, a1 = 0.f, a2 = 0.f, a3 = 0.f, p = 0.f;
  if (slot == 0) {
    ushort4 sv = *(const ushort4*)(h_in + (size_t)dst * 64 + 4 * el);
    a0 = ws * bfbits2f(sv.x);
    a1 = ws * bfbits2f(sv.y);
    a2 = ws * bfbits2f(sv.z);
    a3 = ws * bfbits2f(sv.w);
  }
#pragma unroll 2
  for (int i = slot; i < dg; i += 4) {
    int sn = col_src[rs + i];
    float w = __expf(lrelu(as_[sn] + adv));
    p += w;
    ushort4 sv = *(const ushort4*)(h_in + (size_t)sn * 64 + 4 * el);
    a0 += w * bfbits2f(sv.x);
    a1 += w * bfbits2f(sv.y);
    a2 += w * bfbits2f(sv.z);
    a3 += w * bfbits2f(sv.w);
  }
  a0 += __shfl_xor(a0, 16); a0 += __shfl_xor(a0, 32);
  a1 += __shfl_xor(a1, 16); a1 += __shfl_xor(a1, 32);
  a2 += __shfl_xor(a2, 16); a2 += __shfl_xor(a2, 32);
  a3 += __shfl_xor(a3, 16); a3 += __shfl_xor(a3, 32);
  p  += __shfl_xor(p, 16);  p  += __shfl_xor(p, 32);

  if (slot == 0) {
    const float inv = 1.0f / (p + ws + 1e-16f);
    const bool f = flags[0] != 0;
    float b0, b1, b2, b3;
    if (f) {
      b0 = loadF<true>(bias, 4 * el + 0); b1 = loadF<true>(bias, 4 * el + 1);
      b2 = loadF<true>(bias, 4 * el + 2); b3 = loadF<true>(bias, 4 * el + 3);
    } else {
      b0 = loadF<false>(bias, 4 * el + 0); b1 = loadF<false>(bias, 4 * el + 1);
      b2 = loadF<false>(bias, 4 * el + 2); b3 = loadF<false>(bias, 4 * el + 3);
    }
    float o0 = a0 * inv + b0, o1 = a1 * inv + b1;
    float o2 = a2 * inv + b2, o3 = a3 * inv + b3;
    size_t ob = (size_t)dst * 64 + 4 * el;
    if (f) {
      ushort4 ov;
      ov.x = f2bfbits(o0); ov.y = f2bfbits(o1);
      ov.z = f2bfbits(o2); ov.w = f2bfbits(o3);
      *(ushort4*)((unsigned short*)out + ob) = ov;
    } else {
      float4 ov; ov.x = o0; ov.y = o1; ov.z = o2; ov.w = o3;
      *(float4*)((float*)out + ob) = ov;
    }
  }
}

// ---------------------------------------------------------------------------
extern "C" void kernel_launch(void* const* d_in, const int* in_sizes, int n_in,
                              void* d_out, int out_size, void* d_ws, size_t ws_size,
                              hipStream_t stream) {
  const void* x    = d_in[0];
  const void* ei   = d_in[1];
  const void* W1   = d_in[2];
  const void* as1w = d_in[3];
  const void* ad1w = d_in[4];
  const void* b1   = d_in[5];
  const void* W2   = d_in[6];
  const void* as2w = d_in[7];
  const void* ad2w = d_in[8];
  const void* b2   = d_in[9];

  const int N  = out_size / 64;      // 50000
  const int F  = in_sizes[0] / N;    // 128
  const int E  = in_sizes[1] / 2;    // 800000
  const int H1 = in_sizes[3] / 64;   // 4
  const int D1 = H1 * 64;            // 256
  const int D2 = 64;                 // layer-2 output dim (H2 = 1)

  size_t off = 0;
  auto alloc = [&](size_t bytes) -> void* {
    void* p = (char*)d_ws + off;
    off += (bytes + 255) & ~(size_t)255;
    return p;
  };
  int* flags = (int*)alloc(2 * sizeof(int));
  __hip_bfloat16* h1 = (__hip_bfloat16*)alloc((size_t)N * D1 * 2);
  __hip_bfloat16* x2 = (__hip_bfloat16*)alloc((size_t)N * D1 * 2);
  __hip_bfloat16* h2 = h1;  // h1 dead after layer-1 aggregate; reuse
  unsigned short* xb  = (unsigned short*)alloc((size_t)N * F * 2);   // x in bf16
  unsigned short* w1t = (unsigned short*)alloc((size_t)D1 * F * 2);  // [256][128]
  unsigned short* w2t = (unsigned short*)alloc((size_t)D2 * D1 * 2); // [64][256]
  float* as1 = (float*)alloc((size_t)N * H1 * 4);
  float* ad1 = (float*)alloc((size_t)N * H1 * 4);
  float* wself1 = (float*)alloc((size_t)N * H1 * 4);
  float* as2 = (float*)alloc((size_t)N * 4);
  float* ad2 = (float*)alloc((size_t)N * 4);
  float* wself2 = (float*)alloc((size_t)N * 4);
  int* zero_region = (int*)alloc((size_t)(N + 64) * 4);  // deg | total
  int* deg = zero_region;
  int* total = zero_region + N;
  int* row_start = (int*)alloc((size_t)(N + 1) * 4);
  int* col_src = (int*)alloc((size_t)E * 4);
  int* ppos = (int*)alloc((size_t)E * 4);
  (void)ws_size; (void)n_in;

  const int nb = (N + 255) / 256;
  const int eb = (E + 255) / 256;
  const int db = (N + 3) / 4;
  const int gb = (N + 63) / 64;
  const int nzero = N + 64;
  const int zb = (nzero + 255) / 256;

  const size_t nx = (size_t)N * F;
  const int nb_cast = (int)((nx / 4 + 255) / 256);
  const int nb_t1 = (F * D1 + 255) / 256;
  const int nb_t2 = (D1 * D2 + 255) / 256;

  // 1. dtype detection + zeroing
  detect_zero<<<1 + zb, 256, 0, stream>>>((const uint32_t*)x, (const uint32_t*)ei,
                                          flags, zero_region, nzero);
  // 2. hist (records ppos) || prep (cast skipped when bf16)
  hist_prep<<<eb + nb_cast + nb_t1 + nb_t2, 256, 0, stream>>>(
      ei, E, deg, ppos, x, xb, nx, W1, w1t, F, D1, W2, w2t, D1, D2,
      eb, nb_cast, nb_t1, flags);
  // 3. one-pass scan
  scan_onepass<<<nb, 256, 0, stream>>>(deg, row_start, total, N);
  // 4. scatter (atomic-free) || GEMM1 (64x128 tiles; flattened 2D: gb x 2)
  scatter_gemm1<<<eb + gb * 2, 256, 0, stream>>>(
      ei, E, row_start, ppos, col_src, eb, gb,
      xb, x, w1t, (unsigned short*)h1, as1w, ad1w, as1, ad1, wself1, N, H1, flags);
  // 5. layer-1 aggregate (inline softmax weights)
  aggregate4<<<db, 256, 0, stream>>>((const unsigned short*)h1, wself1, as1, ad1,
                                     row_start, deg, col_src, b1,
                                     (unsigned short*)x2, N, flags);
  // 6. layer-2 GEMM 64x64 tile, K=256 unrolled
  gemm_kernel<256, 4, 1><<<dim3(gb, 1), 256, 0, stream>>>(
      (const unsigned short*)x2, w2t, (unsigned short*)h2, as2w, ad2w,
      as2, ad2, wself2, N, 1, flags);
  // 7. layer-2 aggregate
  aggregate1<<<db, 256, 0, stream>>>((const unsigned short*)h2, wself2, as2, ad2,
                                     row_start, deg, col_src, b2, d_out, N, flags);
}